// Round 4
// baseline (627.171 us; speedup 1.0000x reference)
//
#include <hip/hip_runtime.h>
#include <hip/hip_bf16.h>

// ---------------------------------------------------------------------------
// SingleHeadAttention: b=8, t=2048, e=1024. I/O = float32.
//   Q = (q @ Wq^T)/e^0.25 ; K = (k @ Wk^T)/e^0.25 ; V = v @ Wv^T
//   S = Q K^T (causal) ; P = softmax(S) ; O = P V
// bf16 MFMA internals, f32 accumulate, f32 output.
//
// Round-9: proj A-path restructured (T14 async-split reg-staging).
//  - A staged global(f32)->VGPR->cvt->swizzled ds_write as bf16: LDS tile
//    halves (48->32 KB total -> 4 blocks/CU, was 2.4), inner-loop cvt8 gone
//    (MFMA body now identical to score's proven path).
//  - Next step's A loads issued right AFTER the mid-step __syncthreads (its
//    vmcnt(0) drains only B) and live across a raw lgkmcnt(0)+s_barrier end
//    barrier (no vmcnt drain) -> A latency hidden under frag reads + MFMA.
//    No counted vmcnt anywhere; single-buffered LDS; conservative barriers.
//  - B stays global_load_lds (gload_lds beats reg-staging when usable).
//  - score/out/softmax/cvtW unchanged from round-8 (one structural change
//    per round).
//  - ws: [Q][K][Vt][S]; bf16 weights alias the dead S region during proj.
// ---------------------------------------------------------------------------

typedef short short8 __attribute__((ext_vector_type(8)));   // 8 x bf16
typedef float f32x4 __attribute__((ext_vector_type(4)));
typedef int   int4v __attribute__((ext_vector_type(4)));

static constexpr int B_ = 8;
static constexpr int T_ = 2048;
static constexpr int E_ = 1024;

__device__ __forceinline__ float bf2f(ushort u) {
    union { unsigned int i; float f; } x; x.i = ((unsigned int)u) << 16; return x.f;
}
__device__ __forceinline__ ushort f2bf(float f) {
    union { float f; unsigned int i; } x; x.f = f;
    unsigned int r = x.i + 0x7fffu + ((x.i >> 16) & 1u);   // RNE
    return (ushort)(r >> 16);
}
// packed f32x8 -> bf16x8 (RNE)
__device__ __forceinline__ short8 cvt8(f32x4 a, f32x4 b) {
    short8 r;
    union { __hip_bfloat162 h; unsigned int u; } p;
    unsigned int* ru = (unsigned int*)&r;
    p.h = __float22bfloat162_rn(make_float2(a[0], a[1])); ru[0] = p.u;
    p.h = __float22bfloat162_rn(make_float2(a[2], a[3])); ru[1] = p.u;
    p.h = __float22bfloat162_rn(make_float2(b[0], b[1])); ru[2] = p.u;
    p.h = __float22bfloat162_rn(make_float2(b[2], b[3])); ru[3] = p.u;
    return r;
}

// async 16B global -> LDS; lds base wave-uniform, lane i lands at +16*i.
__device__ __forceinline__ void async16(const ushort* g, ushort* l) {
    __builtin_amdgcn_global_load_lds(
        (const __attribute__((address_space(1))) unsigned int*)g,
        (__attribute__((address_space(3))) unsigned int*)l, 16, 0, 0);
}

// ---------------------------------------------------------------------------
// BK=64 NT GEMM tile: C[128x128] += A[128xK] * B[128xK]^T, bf16, K contig.
// LDS 128x64 per operand (16 KB). Row = 8 granules of 16B; LDS (r,g) holds
// global (r, g ^ (r&7)) -> conflict-free b128 fragment reads (2-way max).
// 1-phase: stage -> barrier(drain) -> compute -> barrier.
__device__ __forceinline__ void gemm_tile64(const ushort* __restrict__ A, int lda,
                                            const ushort* __restrict__ Bm, int ldb,
                                            int ksteps, f32x4 (&acc)[4][4],
                                            ushort* As, ushort* Bs)
{
    const int tid = threadIdx.x, lane = tid & 63, wave = tid >> 6;
    const int wr = (wave >> 1) * 64, wc = (wave & 1) * 64;
    const int srow = lane >> 3;                     // row within 8-row chunk
    const int scol = ((lane & 7) ^ srow) * 8;       // swizzled source col (elems)
    const int frow = lane & 15, q4 = lane >> 4;

    for (int ks = 0; ks < ksteps; ++ks) {
        const int k0 = ks * 64;
        __syncthreads();   // prior iter's ds_reads complete before overwrite
#pragma unroll
        for (int j = 0; j < 4; ++j) {
            const int c = wave * 4 + j;             // 16 chunks per operand
            const int grow = c * 8 + srow;
            async16(A  + (size_t)grow * lda + k0 + scol, As + c * 512);
            async16(Bm + (size_t)grow * ldb + k0 + scol, Bs + c * 512);
        }
        __syncthreads();   // drains vmcnt(0)

        short8 af[4][2], bf[4][2];
#pragma unroll
        for (int i = 0; i < 4; ++i) {
            const int ra = wr + i * 16 + frow;
            const int rb = wc + i * 16 + frow;
            const int sw = frow & 7;
#pragma unroll
            for (int kk = 0; kk < 2; ++kk) {
                const int g = (kk * 4 + q4) ^ sw;
                af[i][kk] = *(const short8*)(As + ra * 64 + g * 8);
                bf[i][kk] = *(const short8*)(Bs + rb * 64 + g * 8);
            }
        }
#pragma unroll
        for (int kk = 0; kk < 2; ++kk)
#pragma unroll
            for (int mi = 0; mi < 4; ++mi)
#pragma unroll
                for (int ni = 0; ni < 4; ++ni)
                    acc[mi][ni] = __builtin_amdgcn_mfma_f32_16x16x32_bf16(
                        af[mi][kk], bf[ni][kk], acc[mi][ni], 0, 0, 0);
    }
}

// ---------------------------------------------------------------------------
// Weight converter: three 1024x1024 f32 -> bf16 (grid.y = 3).
__global__ __launch_bounds__(256)
void cvtW_kernel(const float* __restrict__ w0, const float* __restrict__ w1,
                 const float* __restrict__ w2, ushort* __restrict__ d)
{
    const float* s = blockIdx.y == 0 ? w0 : (blockIdx.y == 1 ? w1 : w2);
    ushort* dd = d + (size_t)blockIdx.y * E_ * E_;
    const int idx = (blockIdx.x * 256 + threadIdx.x) * 8;
    f32x4 a = *(const f32x4*)(s + idx);
    f32x4 b = *(const f32x4*)(s + idx + 4);
    *(short8*)(dd + idx) = cvt8(a, b);
}

// ---------------------------------------------------------------------------
// Stage 1: all three projections, one dispatch. grid (3072). BK=64.
// Flattened block id, XCD-chunked (3072 % 8 == 0 -> bijective), column-
// fastest so the 8 blocks sharing one A f32 row-panel run adjacently on the
// same XCD (A re-reads hit that XCD's L2; measured FETCH ~146 MB).
//
// A path (T14 async-split reg-staging): each thread owns row ar=tid>>1,
// half ah=tid&1 (cols ah*32..+31): 8 f32x4 global loads -> 4 cvt8 ->
// 4 swizzled ds_write_b128 (LDS slot (ah*4+jj)^(ar&7)). The loads for step
// ks+1 are issued right after the mid-step __syncthreads (so its vmcnt(0)
// drains only B) and fly under the frag reads + MFMA; the end-of-step
// barrier is raw lgkmcnt(0)+s_barrier (no vmcnt drain) so they survive it.
// B path: global_load_lds, swizzled source granule, as before.
// LDS 32 KB total -> 4 blocks/CU (VGPR ~112 under launch_bounds(256,4)).
__global__ __launch_bounds__(256, 4)
void proj_kernel(const float* __restrict__ q, const float* __restrict__ k,
                 const float* __restrict__ v, const ushort* __restrict__ Wb,
                 ushort* __restrict__ Q, ushort* __restrict__ Kp,
                 ushort* __restrict__ Vt)
{
    __shared__ ushort As[128 * 64];     // 16 KB (bf16 A tile)
    __shared__ ushort Bs[128 * 64];     // 16 KB

    const int bid = blockIdx.x;
    const int n   = (bid & 7) * 384 + (bid >> 3);   // XCD chunk (3072/8=384)
    const int z   = n >> 10;                         // 0..2 : q,k,v
    const int rem = n & 1023;
    const int by  = rem & 7;                         // W col-block (fastest)
    const int bx  = rem >> 3;                        // A row-panel

    const float* A = (z == 0 ? q : (z == 1 ? k : v)) + (size_t)bx * 128 * E_;
    const ushort* W = Wb + (size_t)z * E_ * E_ + (size_t)by * 128 * E_;

    const int tid = threadIdx.x, lane = tid & 63, wave = tid >> 6;
    const int wr = (wave >> 1) * 64, wc = (wave & 1) * 64;
    // A reg-staging ownership: row ar, col-half ah
    const int ar = tid >> 1;            // 0..127
    const int ah = tid & 1;             // granules ah*4 .. ah*4+3
    // B staging: chunk = 8 rows x 64 bf16 (1024B); lane -> row lane>>3,
    //            LDS granule lane&7, source granule (lane&7)^(row&7).
    const int bRowIn = lane >> 3;
    const int frow = lane & 15, q4 = lane >> 4;

    f32x4 acc[4][4];
#pragma unroll
    for (int i = 0; i < 4; ++i)
#pragma unroll
        for (int j = 0; j < 4; ++j) acc[i][j] = (f32x4){0.f, 0.f, 0.f, 0.f};

    // prologue: A regs for step 0
    f32x4 areg[8];
#pragma unroll
    for (int j = 0; j < 8; ++j)
        areg[j] = *(const f32x4*)(A + (size_t)ar * E_ + ah * 32 + j * 4);

    const int nt = E_ / 64;
    for (int ks = 0; ks < nt; ++ks) {
        const int k0 = ks * 64;
        // ---- staging: B async into LDS, A from regs (cvt -> ds_write) ----
#pragma unroll
        for (int j = 0; j < 4; ++j) {
            const int c = wave * 4 + j;
            const int row = c * 8 + bRowIn;
            const int sg = (lane & 7) ^ (row & 7);
            async16(W + (size_t)row * E_ + k0 + sg * 8, Bs + c * 512);
        }
#pragma unroll
        for (int jj = 0; jj < 4; ++jj) {
            const int slot = (ah * 4 + jj) ^ (ar & 7);
            *(short8*)(As + ar * 64 + slot * 8) = cvt8(areg[2 * jj], areg[2 * jj + 1]);
        }
        __syncthreads();   // vmcnt(0): only B outstanding; lgkm: ds_writes; barrier

        // ---- prefetch A(ks+1): flies under frag reads + MFMA ----
        if (ks + 1 < nt) {
            const int k1 = k0 + 64;
#pragma unroll
            for (int j = 0; j < 8; ++j)
                areg[j] = *(const f32x4*)(A + (size_t)ar * E_ + k1 + ah * 32 + j * 4);
        }
        __builtin_amdgcn_sched_barrier(0);   // pin: loads issued before compute

        // ---- compute (identical to score's proven body) ----
#pragma unroll
        for (int kk = 0; kk < 2; ++kk) {
            short8 af[4], bf[4];
#pragma unroll
            for (int i = 0; i < 4; ++i) {
                const int Ra = wr + i * 16 + frow;
                const int sw = frow & 7;
                const int g = (kk * 4 + q4) ^ sw;
                af[i] = *(const short8*)(As + Ra * 64 + g * 8);
                const int Rb = wc + i * 16 + frow;
                bf[i] = *(const short8*)(Bs + Rb * 64 + g * 8);
            }
#pragma unroll
            for (int mi = 0; mi < 4; ++mi)
#pragma unroll
                for (int ni = 0; ni < 4; ++ni)
                    acc[mi][ni] = __builtin_amdgcn_mfma_f32_16x16x32_bf16(
                        af[mi], bf[ni], acc[mi][ni], 0, 0, 0);
        }
        // ---- end-of-step barrier WITHOUT vmcnt drain (A prefetch stays live)
        asm volatile("s_waitcnt lgkmcnt(0)" ::: "memory");
        __builtin_amdgcn_s_barrier();
        __builtin_amdgcn_sched_barrier(0);
    }

    const float scale = (z == 2) ? 1.0f : 0.17677669529663687f;  // 1/e^(1/4)
    if (z < 2) {
        ushort* D = (z == 0 ? Q : Kp);
#pragma unroll
        for (int mi = 0; mi < 4; ++mi)
#pragma unroll
            for (int r = 0; r < 4; ++r) {
                const int row = bx * 128 + wr + mi * 16 + (lane >> 4) * 4 + r;
#pragma unroll
                for (int ni = 0; ni < 4; ++ni) {
                    const int col = by * 128 + wc + ni * 16 + (lane & 15);
                    D[(size_t)row * E_ + col] = f2bf(acc[mi][ni][r] * scale);
                }
            }
    } else {
#pragma unroll
        for (int mi = 0; mi < 4; ++mi)
#pragma unroll
            for (int r = 0; r < 4; ++r) {
                const int rowg = bx * 128 + wr + mi * 16 + (lane >> 4) * 4 + r;
                const int bb = rowg >> 11, tl = rowg & 2047;
#pragma unroll
                for (int ni = 0; ni < 4; ++ni) {
                    const int col = by * 128 + wc + ni * 16 + (lane & 15);
                    Vt[(size_t)bb * E_ * T_ + (size_t)col * T_ + tl] = f2bf(acc[mi][ni][r]);
                }
            }
    }
}

// ---------------------------------------------------------------------------
// Stage 2: S = Q K^T causal. Compact lower-triangle grid (136, 8), XCD-chunked
// (136 = 8*17, bijective) so same-br runs (sharing a Q panel) stay on one XCD.
__global__ __launch_bounds__(256, 2)
void score_kernel(const ushort* __restrict__ Q, const ushort* __restrict__ K,
                  ushort* __restrict__ S)
{
    __shared__ ushort As[128 * 64];
    __shared__ ushort Bs[128 * 64];
    const int b = blockIdx.y;
    const int t = (blockIdx.x & 7) * 17 + (blockIdx.x >> 3);   // 136/8 = 17
    int br = (int)((sqrtf(8.0f * t + 1.0f) - 1.0f) * 0.5f);
    while ((br + 1) * (br + 2) / 2 <= t) ++br;
    while (br * (br + 1) / 2 > t) --br;
    const int bc = t - br * (br + 1) / 2;

    const ushort* A  = Q + ((size_t)b * T_ + br * 128) * E_;
    const ushort* Bm = K + ((size_t)b * T_ + bc * 128) * E_;

    f32x4 acc[4][4];
#pragma unroll
    for (int i = 0; i < 4; ++i)
#pragma unroll
        for (int j = 0; j < 4; ++j) acc[i][j] = (f32x4){0.f, 0.f, 0.f, 0.f};

    gemm_tile64(A, E_, Bm, E_, E_ / 64, acc, As, Bs);

    const int lane = threadIdx.x & 63, wave = threadIdx.x >> 6;
    const int wr = (wave >> 1) * 64, wc = (wave & 1) * 64;
    ushort* Sb = S + (size_t)b * T_ * T_;
#pragma unroll
    for (int mi = 0; mi < 4; ++mi)
#pragma unroll
        for (int r = 0; r < 4; ++r) {
            const int row = br * 128 + wr + mi * 16 + (lane >> 4) * 4 + r;
#pragma unroll
            for (int ni = 0; ni < 4; ++ni) {
                const int col = bc * 128 + wc + ni * 16 + (lane & 15);
                float val = acc[mi][ni][r];
                if (col > row) val = -1e30f;
                Sb[(size_t)row * T_ + col] = f2bf(val);
            }
        }
}

// ---------------------------------------------------------------------------
// Stage 3: row softmax in place, 16B vector I/O. One block per row.
__global__ __launch_bounds__(256)
void softmax_kernel(ushort* __restrict__ S)
{
    const int gr = blockIdx.x;
    const int b = gr >> 11, i = gr & 2047;
    ushort* row = S + (size_t)b * T_ * T_ + (size_t)i * T_;
    const int Lpad = ((i >> 7) + 1) * 128;
    const int tid = threadIdx.x, lane = tid & 63, wave = tid >> 6;
    __shared__ float red[4];

    const int j0 = tid * 8;
    const bool act = j0 < Lpad;
    float xv[8];
    if (act) {
        int4v dv = *(const int4v*)(row + j0);
        const ushort* u = (const ushort*)&dv;
#pragma unroll
        for (int t = 0; t < 8; ++t) xv[t] = bf2f(u[t]);
    }

    float m = -1e30f;
    if (act)
#pragma unroll
        for (int t = 0; t < 8; ++t) m = fmaxf(m, xv[t]);
#pragma unroll
    for (int o = 32; o; o >>= 1) m = fmaxf(m, __shfl_xor(m, o, 64));
    if (lane == 0) red[wave] = m;
    __syncthreads();
    m = fmaxf(fmaxf(red[0], red[1]), fmaxf(red[2], red[3]));
    __syncthreads();

    float s = 0.f;
    if (act)
#pragma unroll
        for (int t = 0; t < 8; ++t) { xv[t] = __expf(xv[t] - m); s += xv[t]; }
#pragma unroll
    for (int o = 32; o; o >>= 1) s += __shfl_xor(s, o, 64);
    if (lane == 0) red[wave] = s;
    __syncthreads();
    s = red[0] + red[1] + red[2] + red[3];
    const float inv = 1.0f / s;

    if (act) {
        int4v dv;
        ushort* u = (ushort*)&dv;
#pragma unroll
        for (int t = 0; t < 8; ++t) u[t] = f2bf(xv[t] * inv);
        *(int4v*)(row + j0) = dv;
    }
}

// ---------------------------------------------------------------------------
// Stage 4: O = P @ V via V^T (NT, BK=64, 1-phase). grid (8, 16, 8). f32 out.
// br reversed so the longest causal blocks (br=15, 32 ksteps) dispatch first.
__global__ __launch_bounds__(256, 2)
void out_kernel(const ushort* __restrict__ P, const ushort* __restrict__ Vt,
                float* __restrict__ O)
{
    __shared__ ushort As[128 * 64];
    __shared__ ushort Bs[128 * 64];
    const int bc = blockIdx.x, b = blockIdx.z;
    const int br = (int)gridDim.y - 1 - (int)blockIdx.y;   // longest first
    const ushort* A  = P  + (size_t)b * T_ * T_ + (size_t)(br * 128) * T_;
    const ushort* Bm = Vt + (size_t)b * E_ * T_ + (size_t)(bc * 128) * T_;
    const int ksteps = (br + 1) * 2;   // causal K-limit, BK=64

    f32x4 acc[4][4];
#pragma unroll
    for (int i = 0; i < 4; ++i)
#pragma unroll
        for (int j = 0; j < 4; ++j) acc[i][j] = (f32x4){0.f, 0.f, 0.f, 0.f};

    gemm_tile64(A, T_, Bm, T_, ksteps, acc, As, Bs);

    const int lane = threadIdx.x & 63, wave = threadIdx.x >> 6;
    const int wr = (wave >> 1) * 64, wc = (wave & 1) * 64;
    float* Ob = O + (size_t)b * T_ * E_;
#pragma unroll
    for (int mi = 0; mi < 4; ++mi)
#pragma unroll
        for (int r = 0; r < 4; ++r) {
            const int row = br * 128 + wr + mi * 16 + (lane >> 4) * 4 + r;
#pragma unroll
            for (int ni = 0; ni < 4; ++ni) {
                const int col = bc * 128 + wc + ni * 16 + (lane & 15);
                Ob[(size_t)row * E_ + col] = acc[mi][ni][r];
            }
        }
}

// ---------------------------------------------------------------------------
extern "C" void kernel_launch(void* const* d_in, const int* in_sizes, int n_in,
                              void* d_out, int out_size, void* d_ws, size_t ws_size,
                              hipStream_t stream)
{
    const float* q  = (const float*)d_in[0];
    const float* k  = (const float*)d_in[1];
    const float* v  = (const float*)d_in[2];
    const float* Wq = (const float*)d_in[3];
    const float* Wk = (const float*)d_in[4];
    const float* Wv = (const float*)d_in[5];
    float* out = (float*)d_out;

    const size_t nQKV = (size_t)B_ * T_ * E_;      // 16,777,216 elems
    const size_t nW   = (size_t)E_ * E_;
    ushort* Q  = (ushort*)d_ws;
    ushort* K  = Q + nQKV;
    ushort* Vt = K + nQKV;
    ushort* S  = Vt + nQKV;                        // 67 MB
    ushort* Wb = S;                                // weights alias dead S region

    cvtW_kernel<<<dim3(nW / 2048, 3), 256, 0, stream>>>(Wq, Wk, Wv, Wb);
    proj_kernel<<<dim3(3072), 256, 0, stream>>>(q, k, v, Wb, Q, K, Vt);
    score_kernel<<<dim3(136, B_), 256, 0, stream>>>(Q, K, S);
    softmax_kernel<<<dim3(B_ * T_), 256, 0, stream>>>(S);
    out_kernel<<<dim3(E_ / 128, T_ / 128, B_), 256, 0, stream>>>(S, Vt, out);
}

// Round 5
// 503.553 us; speedup vs baseline: 1.2455x; 1.2455x over previous
//
#include <hip/hip_runtime.h>
#include <hip/hip_bf16.h>

// ---------------------------------------------------------------------------
// SingleHeadAttention: b=8, t=2048, e=1024. I/O = float32.
//   Q = (q @ Wq^T)/e^0.25 ; K = (k @ Wk^T)/e^0.25 ; V = v @ Wv^T
//   S = Q K^T (causal) ; P = softmax(S) ; O = P V
// bf16 MFMA internals, f32 accumulate, f32 output.
//
// Round-10: counted-vmcnt double-buffered pipeline (T3+T4) in all GEMMs.
//  - STATIC dbuf arrays (As0/As1...), loop unrolled x2 so buffer names are
//    compile-time (r2's __syncthreads+runtime-index dbuf made the compiler
//    emit vmcnt(0) before ds_reads -> serialization; this dodges it).
//  - Per K-tile: stage(next tile) -> vmcnt(N) [N = loads/tile, keeps the
//    just-issued loads in flight, waits only the previous tile's] ->
//    s_barrier -> compute -> lgkmcnt(0) -> s_barrier. Last tile: vmcnt(0).
//    Staging latency hides under the whole MFMA phase (m218 pattern).
//  - Staging addressing = the proven chunked gload_lds (r4's per-lane
//    scatter loads were the regression; reverted).
//  - proj: round-1 grid (128,8,3) (its fastest), BK=32 dbuf (48 KB, 3 blk/CU).
//  - score/out: BK=64 dbuf (64 KB, 2 blk/CU). score: XCD-chunked triangle.
//  - ws: [Q][K][Vt][S]; bf16 weights alias the dead S region during proj.
// ---------------------------------------------------------------------------

typedef short short8 __attribute__((ext_vector_type(8)));   // 8 x bf16
typedef float f32x4 __attribute__((ext_vector_type(4)));
typedef int   int4v __attribute__((ext_vector_type(4)));

static constexpr int B_ = 8;
static constexpr int T_ = 2048;
static constexpr int E_ = 1024;

#define WAITVM8  asm volatile("s_waitcnt vmcnt(8)" ::: "memory")
#define WAITVM6  asm volatile("s_waitcnt vmcnt(6)" ::: "memory")
#define WAITVM0  asm volatile("s_waitcnt vmcnt(0)" ::: "memory")
#define WAITLGKM asm volatile("s_waitcnt lgkmcnt(0)" ::: "memory")
#define BARRIER  { __builtin_amdgcn_s_barrier(); __builtin_amdgcn_sched_barrier(0); }

__device__ __forceinline__ float bf2f(ushort u) {
    union { unsigned int i; float f; } x; x.i = ((unsigned int)u) << 16; return x.f;
}
__device__ __forceinline__ ushort f2bf(float f) {
    union { float f; unsigned int i; } x; x.f = f;
    unsigned int r = x.i + 0x7fffu + ((x.i >> 16) & 1u);   // RNE
    return (ushort)(r >> 16);
}
// packed f32x8 -> bf16x8 (RNE)
__device__ __forceinline__ short8 cvt8(f32x4 a, f32x4 b) {
    short8 r;
    union { __hip_bfloat162 h; unsigned int u; } p;
    unsigned int* ru = (unsigned int*)&r;
    p.h = __float22bfloat162_rn(make_float2(a[0], a[1])); ru[0] = p.u;
    p.h = __float22bfloat162_rn(make_float2(a[2], a[3])); ru[1] = p.u;
    p.h = __float22bfloat162_rn(make_float2(b[0], b[1])); ru[2] = p.u;
    p.h = __float22bfloat162_rn(make_float2(b[2], b[3])); ru[3] = p.u;
    return r;
}

// async 16B global -> LDS; lds base wave-uniform, lane i lands at +16*i.
__device__ __forceinline__ void async16(const ushort* g, ushort* l) {
    __builtin_amdgcn_global_load_lds(
        (const __attribute__((address_space(1))) unsigned int*)g,
        (__attribute__((address_space(3))) unsigned int*)l, 16, 0, 0);
}
__device__ __forceinline__ void async16f(const float* g, float* l) {
    __builtin_amdgcn_global_load_lds(
        (const __attribute__((address_space(1))) unsigned int*)g,
        (__attribute__((address_space(3))) unsigned int*)l, 16, 0, 0);
}

// ---------------------------------------------------------------------------
// BK=64 staging: one 128x64 bf16 tile per operand into (As,Bs).
// Row = 8 granules of 16B; LDS (r,g) holds global (r, g ^ (r&7)).
// 8 gload_lds per thread (4 A + 4 B, interleaved) -> vmcnt unit = 8.
__device__ __forceinline__ void stage64(const ushort* __restrict__ A, int lda,
                                        const ushort* __restrict__ Bm, int ldb,
                                        int k0, ushort* As, ushort* Bs,
                                        int wave, int srow, int scol)
{
#pragma unroll
    for (int j = 0; j < 4; ++j) {
        const int c = wave * 4 + j;                 // 16 chunks per operand
        const int grow = c * 8 + srow;
        async16(A  + (size_t)grow * lda + k0 + scol, As + c * 512);
        async16(Bm + (size_t)grow * ldb + k0 + scol, Bs + c * 512);
    }
}

// BK=64 compute: 32 MFMA from (As,Bs) into acc. Frag reads undo the swizzle.
__device__ __forceinline__ void compute64(const ushort* As, const ushort* Bs,
                                          f32x4 (&acc)[4][4],
                                          int wr, int wc, int frow, int q4)
{
    short8 af[4][2], bf[4][2];
#pragma unroll
    for (int i = 0; i < 4; ++i) {
        const int ra = wr + i * 16 + frow;
        const int rb = wc + i * 16 + frow;
        const int sw = frow & 7;
#pragma unroll
        for (int kk = 0; kk < 2; ++kk) {
            const int g = (kk * 4 + q4) ^ sw;
            af[i][kk] = *(const short8*)(As + ra * 64 + g * 8);
            bf[i][kk] = *(const short8*)(Bs + rb * 64 + g * 8);
        }
    }
#pragma unroll
    for (int kk = 0; kk < 2; ++kk)
#pragma unroll
        for (int mi = 0; mi < 4; ++mi)
#pragma unroll
            for (int ni = 0; ni < 4; ++ni)
                acc[mi][ni] = __builtin_amdgcn_mfma_f32_16x16x32_bf16(
                    af[mi][kk], bf[ni][kk], acc[mi][ni], 0, 0, 0);
}

// Counted-vmcnt pipelined NT GEMM over static dbuf. ksteps EVEN.
// Iter: stage(next) -> vmcnt(8) -> bar -> compute(cur) -> lgkm(0) -> bar.
__device__ __forceinline__ void gemm_pipe64(const ushort* __restrict__ A, int lda,
                                            const ushort* __restrict__ Bm, int ldb,
                                            int ksteps, f32x4 (&acc)[4][4],
                                            ushort* As0, ushort* Bs0,
                                            ushort* As1, ushort* Bs1)
{
    const int tid = threadIdx.x, lane = tid & 63, wave = tid >> 6;
    const int wr = (wave >> 1) * 64, wc = (wave & 1) * 64;
    const int srow = lane >> 3;
    const int scol = ((lane & 7) ^ srow) * 8;
    const int frow = lane & 15, q4 = lane >> 4;

    stage64(A, lda, Bm, ldb, 0, As0, Bs0, wave, srow, scol);   // tile 0

    for (int kt = 0; kt < ksteps; kt += 2) {
        // even half: compute buf0 (tile kt), stage tile kt+1 -> buf1
        stage64(A, lda, Bm, ldb, (kt + 1) * 64, As1, Bs1, wave, srow, scol);
        WAITVM8;                       // tile kt resident; kt+1 in flight
        BARRIER;
        compute64(As0, Bs0, acc, wr, wc, frow, q4);
        WAITLGKM;
        BARRIER;
        // odd half: compute buf1 (tile kt+1), stage tile kt+2 -> buf0
        if (kt + 2 < ksteps) {
            stage64(A, lda, Bm, ldb, (kt + 2) * 64, As0, Bs0, wave, srow, scol);
            WAITVM8;
        } else {
            WAITVM0;                   // final tile: drain
        }
        BARRIER;
        compute64(As1, Bs1, acc, wr, wc, frow, q4);
        WAITLGKM;
        BARRIER;
    }
}

// ---------------------------------------------------------------------------
// Weight converter: three 1024x1024 f32 -> bf16 (grid.y = 3).
__global__ __launch_bounds__(256)
void cvtW_kernel(const float* __restrict__ w0, const float* __restrict__ w1,
                 const float* __restrict__ w2, ushort* __restrict__ d)
{
    const float* s = blockIdx.y == 0 ? w0 : (blockIdx.y == 1 ? w1 : w2);
    ushort* dd = d + (size_t)blockIdx.y * E_ * E_;
    const int idx = (blockIdx.x * 256 + threadIdx.x) * 8;
    f32x4 a = *(const f32x4*)(s + idx);
    f32x4 b = *(const f32x4*)(s + idx + 4);
    *(short8*)(dd + idx) = cvt8(a, b);
}

// ---------------------------------------------------------------------------
// Stage 1: all three projections. grid (128, 8, 3) (round-1's fastest).
// BK=32, counted-vmcnt dbuf: A 128x32 f32 (16KB x2), B 128x32 bf16 (8KB x2)
// = 48 KB -> 3 blocks/CU. 6 gload_lds per thread per tile -> vmcnt unit 6.
// A swz: 8 granules/row, src granule (lane&7)^row.
// B swz: 4 granules/row, src granule (lane&3)^((lane>>3)&3).
__global__ __launch_bounds__(256, 2)
void proj_kernel(const float* __restrict__ q, const float* __restrict__ k,
                 const float* __restrict__ v, const ushort* __restrict__ Wb,
                 ushort* __restrict__ Q, ushort* __restrict__ Kp,
                 ushort* __restrict__ Vt)
{
    __shared__ float  Asf0[128 * 32], Asf1[128 * 32];   // 16 KB each
    __shared__ ushort Bs0[128 * 32],  Bs1[128 * 32];    //  8 KB each

    const int bx = blockIdx.x, by = blockIdx.y, z = blockIdx.z;
    const float* A = (z == 0 ? q : (z == 1 ? k : v)) + (size_t)bx * 128 * E_;
    const ushort* W = Wb + (size_t)z * E_ * E_ + (size_t)by * 128 * E_;

    const int tid = threadIdx.x, lane = tid & 63, wave = tid >> 6;
    const int wr = (wave >> 1) * 64, wc = (wave & 1) * 64;
    const int sArow = lane >> 3;
    const int sAcol = ((lane & 7) ^ sArow) * 4;
    const int sBrow = lane >> 2;
    const int sBcol = ((lane & 3) ^ ((lane >> 3) & 3)) * 8;
    const int frow = lane & 15, q4 = lane >> 4;

    f32x4 acc[4][4];
#pragma unroll
    for (int i = 0; i < 4; ++i)
#pragma unroll
        for (int j = 0; j < 4; ++j) acc[i][j] = (f32x4){0.f, 0.f, 0.f, 0.f};

    // staging: 4 A chunks + 2 B chunks per thread = 6 gload_lds
#define PROJ_STAGE(k0, Asf, Bs)                                               \
    {                                                                         \
        _Pragma("unroll")                                                     \
        for (int j = 0; j < 4; ++j) {                                         \
            const int c = wave * 4 + j;                                       \
            async16f(A + (size_t)(c * 8 + sArow) * E_ + (k0) + sAcol,         \
                     (Asf) + c * 256);                                        \
        }                                                                     \
        _Pragma("unroll")                                                     \
        for (int j = 0; j < 2; ++j) {                                         \
            const int c = wave * 2 + j;                                       \
            async16(W + (size_t)(c * 16 + sBrow) * E_ + (k0) + sBcol,         \
                    (Bs) + c * 512);                                          \
        }                                                                     \
    }

#define PROJ_COMPUTE(Asf, Bs)                                                 \
    {                                                                         \
        short8 af[4], bf[4];                                                  \
        _Pragma("unroll")                                                     \
        for (int i = 0; i < 4; ++i) {                                         \
            const int R = wr + i * 16 + frow;                                 \
            const int g0 = (q4 * 2) ^ (frow & 7);                             \
            const int g1 = g0 ^ 1;                                            \
            f32x4 lo = *(const f32x4*)((Asf) + R * 32 + g0 * 4);              \
            f32x4 hi = *(const f32x4*)((Asf) + R * 32 + g1 * 4);              \
            af[i] = cvt8(lo, hi);                                             \
        }                                                                     \
        _Pragma("unroll")                                                     \
        for (int i = 0; i < 4; ++i) {                                         \
            const int R = wc + i * 16 + frow;                                 \
            const int g = q4 ^ ((frow >> 1) & 3);                             \
            bf[i] = *(const short8*)((Bs) + R * 32 + g * 8);                  \
        }                                                                     \
        _Pragma("unroll")                                                     \
        for (int mi = 0; mi < 4; ++mi)                                        \
            _Pragma("unroll")                                                 \
            for (int ni = 0; ni < 4; ++ni)                                    \
                acc[mi][ni] = __builtin_amdgcn_mfma_f32_16x16x32_bf16(        \
                    af[mi], bf[ni], acc[mi][ni], 0, 0, 0);                    \
    }

    PROJ_STAGE(0, Asf0, Bs0);                       // tile 0
    const int nt = E_ / 32;                         // 32, even
    for (int kt = 0; kt < nt; kt += 2) {
        PROJ_STAGE((kt + 1) * 32, Asf1, Bs1);
        WAITVM6;
        BARRIER;
        PROJ_COMPUTE(Asf0, Bs0);
        WAITLGKM;
        BARRIER;
        if (kt + 2 < nt) {
            PROJ_STAGE((kt + 2) * 32, Asf0, Bs0);
            WAITVM6;
        } else {
            WAITVM0;
        }
        BARRIER;
        PROJ_COMPUTE(Asf1, Bs1);
        WAITLGKM;
        BARRIER;
    }
#undef PROJ_STAGE
#undef PROJ_COMPUTE

    const float scale = (z == 2) ? 1.0f : 0.17677669529663687f;  // 1/e^(1/4)
    if (z < 2) {
        ushort* D = (z == 0 ? Q : Kp);
#pragma unroll
        for (int mi = 0; mi < 4; ++mi)
#pragma unroll
            for (int r = 0; r < 4; ++r) {
                const int row = bx * 128 + wr + mi * 16 + (lane >> 4) * 4 + r;
#pragma unroll
                for (int ni = 0; ni < 4; ++ni) {
                    const int col = by * 128 + wc + ni * 16 + (lane & 15);
                    D[(size_t)row * E_ + col] = f2bf(acc[mi][ni][r] * scale);
                }
            }
    } else {
#pragma unroll
        for (int mi = 0; mi < 4; ++mi)
#pragma unroll
            for (int r = 0; r < 4; ++r) {
                const int rowg = bx * 128 + wr + mi * 16 + (lane >> 4) * 4 + r;
                const int bb = rowg >> 11, tl = rowg & 2047;
#pragma unroll
                for (int ni = 0; ni < 4; ++ni) {
                    const int col = by * 128 + wc + ni * 16 + (lane & 15);
                    Vt[(size_t)bb * E_ * T_ + (size_t)col * T_ + tl] = f2bf(acc[mi][ni][r]);
                }
            }
    }
}

// ---------------------------------------------------------------------------
// Stage 2: S = Q K^T causal. Compact lower-triangle grid (136, 8), XCD-chunked
// (136 = 8*17, bijective). Pipelined BK=64 (ksteps=16, even).
__global__ __launch_bounds__(256, 2)
void score_kernel(const ushort* __restrict__ Q, const ushort* __restrict__ K,
                  ushort* __restrict__ S)
{
    __shared__ ushort As0[128 * 64], Bs0[128 * 64];   // 16 KB each
    __shared__ ushort As1[128 * 64], Bs1[128 * 64];   // total 64 KB
    const int b = blockIdx.y;
    const int t = (blockIdx.x & 7) * 17 + (blockIdx.x >> 3);   // 136/8 = 17
    int br = (int)((sqrtf(8.0f * t + 1.0f) - 1.0f) * 0.5f);
    while ((br + 1) * (br + 2) / 2 <= t) ++br;
    while (br * (br + 1) / 2 > t) --br;
    const int bc = t - br * (br + 1) / 2;

    const ushort* A  = Q + ((size_t)b * T_ + br * 128) * E_;
    const ushort* Bm = K + ((size_t)b * T_ + bc * 128) * E_;

    f32x4 acc[4][4];
#pragma unroll
    for (int i = 0; i < 4; ++i)
#pragma unroll
        for (int j = 0; j < 4; ++j) acc[i][j] = (f32x4){0.f, 0.f, 0.f, 0.f};

    gemm_pipe64(A, E_, Bm, E_, E_ / 64, acc, As0, Bs0, As1, Bs1);

    const int lane = threadIdx.x & 63, wave = threadIdx.x >> 6;
    const int wr = (wave >> 1) * 64, wc = (wave & 1) * 64;
    ushort* Sb = S + (size_t)b * T_ * T_;
#pragma unroll
    for (int mi = 0; mi < 4; ++mi)
#pragma unroll
        for (int r = 0; r < 4; ++r) {
            const int row = br * 128 + wr + mi * 16 + (lane >> 4) * 4 + r;
#pragma unroll
            for (int ni = 0; ni < 4; ++ni) {
                const int col = bc * 128 + wc + ni * 16 + (lane & 15);
                float val = acc[mi][ni][r];
                if (col > row) val = -1e30f;
                Sb[(size_t)row * T_ + col] = f2bf(val);
            }
        }
}

// ---------------------------------------------------------------------------
// Stage 3: row softmax in place, 16B vector I/O. One block per row.
__global__ __launch_bounds__(256)
void softmax_kernel(ushort* __restrict__ S)
{
    const int gr = blockIdx.x;
    const int b = gr >> 11, i = gr & 2047;
    ushort* row = S + (size_t)b * T_ * T_ + (size_t)i * T_;
    const int Lpad = ((i >> 7) + 1) * 128;
    const int tid = threadIdx.x, lane = tid & 63, wave = tid >> 6;
    __shared__ float red[4];

    const int j0 = tid * 8;
    const bool act = j0 < Lpad;
    float xv[8];
    if (act) {
        int4v dv = *(const int4v*)(row + j0);
        const ushort* u = (const ushort*)&dv;
#pragma unroll
        for (int t = 0; t < 8; ++t) xv[t] = bf2f(u[t]);
    }

    float m = -1e30f;
    if (act)
#pragma unroll
        for (int t = 0; t < 8; ++t) m = fmaxf(m, xv[t]);
#pragma unroll
    for (int o = 32; o; o >>= 1) m = fmaxf(m, __shfl_xor(m, o, 64));
    if (lane == 0) red[wave] = m;
    __syncthreads();
    m = fmaxf(fmaxf(red[0], red[1]), fmaxf(red[2], red[3]));
    __syncthreads();

    float s = 0.f;
    if (act)
#pragma unroll
        for (int t = 0; t < 8; ++t) { xv[t] = __expf(xv[t] - m); s += xv[t]; }
#pragma unroll
    for (int o = 32; o; o >>= 1) s += __shfl_xor(s, o, 64);
    if (lane == 0) red[wave] = s;
    __syncthreads();
    s = red[0] + red[1] + red[2] + red[3];
    const float inv = 1.0f / s;

    if (act) {
        int4v dv;
        ushort* u = (ushort*)&dv;
#pragma unroll
        for (int t = 0; t < 8; ++t) u[t] = f2bf(xv[t] * inv);
        *(int4v*)(row + j0) = dv;
    }
}

// ---------------------------------------------------------------------------
// Stage 4: O = P @ V via V^T (NT, BK=64, pipelined). grid (8, 16, 8). f32 out.
// ksteps = (br+1)*2 is always even. Longest causal blocks dispatch first.
__global__ __launch_bounds__(256, 2)
void out_kernel(const ushort* __restrict__ P, const ushort* __restrict__ Vt,
                float* __restrict__ O)
{
    __shared__ ushort As0[128 * 64], Bs0[128 * 64];
    __shared__ ushort As1[128 * 64], Bs1[128 * 64];
    const int bc = blockIdx.x, b = blockIdx.z;
    const int br = (int)gridDim.y - 1 - (int)blockIdx.y;   // longest first
    const ushort* A  = P  + (size_t)b * T_ * T_ + (size_t)(br * 128) * T_;
    const ushort* Bm = Vt + (size_t)b * E_ * T_ + (size_t)(bc * 128) * T_;
    const int ksteps = (br + 1) * 2;   // causal K-limit, BK=64

    f32x4 acc[4][4];
#pragma unroll
    for (int i = 0; i < 4; ++i)
#pragma unroll
        for (int j = 0; j < 4; ++j) acc[i][j] = (f32x4){0.f, 0.f, 0.f, 0.f};

    gemm_pipe64(A, T_, Bm, T_, ksteps, acc, As0, Bs0, As1, Bs1);

    const int lane = threadIdx.x & 63, wave = threadIdx.x >> 6;
    const int wr = (wave >> 1) * 64, wc = (wave & 1) * 64;
    float* Ob = O + (size_t)b * T_ * E_;
#pragma unroll
    for (int mi = 0; mi < 4; ++mi)
#pragma unroll
        for (int r = 0; r < 4; ++r) {
            const int row = br * 128 + wr + mi * 16 + (lane >> 4) * 4 + r;
#pragma unroll
            for (int ni = 0; ni < 4; ++ni) {
                const int col = bc * 128 + wc + ni * 16 + (lane & 15);
                Ob[(size_t)row * E_ + col] = acc[mi][ni][r];
            }
        }
}

// ---------------------------------------------------------------------------
extern "C" void kernel_launch(void* const* d_in, const int* in_sizes, int n_in,
                              void* d_out, int out_size, void* d_ws, size_t ws_size,
                              hipStream_t stream)
{
    const float* q  = (const float*)d_in[0];
    const float* k  = (const float*)d_in[1];
    const float* v  = (const float*)d_in[2];
    const float* Wq = (const float*)d_in[3];
    const float* Wk = (const float*)d_in[4];
    const float* Wv = (const float*)d_in[5];
    float* out = (float*)d_out;

    const size_t nQKV = (size_t)B_ * T_ * E_;      // 16,777,216 elems
    const size_t nW   = (size_t)E_ * E_;
    ushort* Q  = (ushort*)d_ws;
    ushort* K  = Q + nQKV;
    ushort* Vt = K + nQKV;
    ushort* S  = Vt + nQKV;                        // 67 MB
    ushort* Wb = S;                                // weights alias dead S region

    cvtW_kernel<<<dim3(nW / 2048, 3), 256, 0, stream>>>(Wq, Wk, Wv, Wb);
    proj_kernel<<<dim3(128, 8, 3), 256, 0, stream>>>(q, k, v, Wb, Q, K, Vt);
    score_kernel<<<dim3(136, B_), 256, 0, stream>>>(Q, K, S);
    softmax_kernel<<<dim3(B_ * T_), 256, 0, stream>>>(S);
    out_kernel<<<dim3(E_ / 128, T_ / 128, B_), 256, 0, stream>>>(S, Vt, out);
}